// Round 6
// baseline (691.121 us; speedup 1.0000x reference)
//
#include <hip/hip_runtime.h>
#include <hip/hip_cooperative_groups.h>

namespace cg = cooperative_groups;

// GCNConv + ReLU, MI355X. fp32 tensors, edge_index int32.
// out[d] = relu(dn * (h[d]*dn + sum_{e:dst=d} h[src_e]*dis[src_e]) + b),
//   h = x@W (UNSCALED bf16), dis[i] = rsqrt(cnt[i]+1), dn = dis[d].
// R3: CSR + register aggregation (no float atomics)            531us
// R4: [gemm|scatter] fused 1:2 + bf16 h                        398us
// R5 FAILED (735us): split kernels serialize on the stream.
// R8: stride-64 buckets via atomicAdd (3 launches).             334us
// R9: GEMM VALU->MFMA (3-term bf16 split, swizzled W blob).     327us
// R10 FAILED (421us): 8 edges/thread serialized atomic chains.
// R11: nontemporal scatter/stream traffic. fused 131->114.      321us
// R12: two-level binning: fused 114->80, WRITE 123->60MB, BUT   337us
//     total +16: the added memset+prep launches/drains (~50us) ate the
//     win. Per-kernel pipes all <20% busy -> time is in the SEAMS
//     (launch overhead + full drain per stage), not the kernels.
// R13: one cooperative mega-kernel [zero+wprep | sync | bin-pass |
//     sync | bucket||gemm] via grid.sync(); aggr stays separate for
//     TLP. 4 stream ops -> 2. Bin pass restructured: no LDS staging
//     (re-read L1-hot chunk), 4x per-wave counters vs contention.

typedef __attribute__((ext_vector_type(8))) short bf16x8;
typedef __attribute__((ext_vector_type(4))) float f32x4;
typedef __attribute__((ext_vector_type(2))) unsigned int u32x2;

__device__ __forceinline__ unsigned short f2bf(float f) {
  unsigned int u = __float_as_uint(f);
  u += 0x7FFFu + ((u >> 16) & 1u);   // RNE
  return (unsigned short)(u >> 16);
}
__device__ __forceinline__ float bfval(unsigned short h) {
  return __uint_as_float(((unsigned int)h) << 16);
}
__device__ __forceinline__ float bf0(unsigned int u) { return __uint_as_float(u << 16); }
__device__ __forceinline__ float bf1(unsigned int u) { return __uint_as_float(u & 0xFFFF0000u); }

#define EPB 4096            // edges per bin-pass virtual block
#define MAXB 256            // max bins

// ---------------- shared device bodies ----------------

__device__ __forceinline__ void wprep_elem(const float* __restrict__ W,
                                           unsigned short* __restrict__ blob, int g) {
  int k = g >> 7, c = g & 127;
  float w = W[g];
  unsigned short hi = f2bf(w);
  unsigned short lo = f2bf(w - bfval(hi));
  int q = k >> 5, kk = k & 31;
  unsigned lin = (unsigned)(c * 64 + kk * 2);
  unsigned swz = lin ^ (((unsigned)(c & 7)) << 4);
  blob[(q * 16384 + swz) >> 1] = hi;
  blob[(q * 16384 + 8192 + swz) >> 1] = lo;
}

// bucket build body: replay bin pairs with LDS atomics into the bin's
// private srcs window; write cnt once per node. smem >= 2048B.
__device__ __forceinline__ void bucket_body(
    unsigned char* smem, int bin, int tid,
    const u32x2* __restrict__ pairs, const unsigned int* __restrict__ binTail,
    unsigned int* __restrict__ cnt, int* __restrict__ srcs,
    int N, int shift, int cap)
{
  unsigned int* lcnt = (unsigned int*)smem;     // [1<<shift]
  const int bsz = 1 << shift;
  const int nbase = bin << shift;
  const int nn = min(bsz, N - nbase);
  if (nn <= 0) return;
  for (int i = tid; i < bsz; i += 256) lcnt[i] = 0u;
  __syncthreads();
  const int n = min((int)binTail[bin], cap);
  const u32x2* bp = pairs + (size_t)bin * cap;
  for (int p = tid; p < n; p += 256) {
    const u32x2 pr = bp[p];
    const unsigned pos = atomicAdd(&lcnt[pr.x], 1u);
    if (pos < 64)
      srcs[(((size_t)(nbase + pr.x)) << 6) + pos] = (int)pr.y;
  }
  __syncthreads();
  for (int i = tid; i < nn; i += 256) cnt[nbase + i] = lcnt[i];
}

// gemm tile body (R12-proven): tile 32 rows x 128 cols, K-chunk 32,
// 3-term bf16 split on mfma_f32_16x16x32_bf16.
// A/B lane l: 8 contig k = 8*(l>>4)+j; C/D: col=l&15, row=4*(l>>4)+reg.
__device__ __forceinline__ void gemm_body(
    unsigned char* smem, int idx, int tid,
    const float* __restrict__ x, const unsigned char* __restrict__ wblob,
    unsigned short* __restrict__ h, int N)
{
  const int row0 = idx * 32;
  const int lane = tid & 63;
  const int wv = tid >> 6;
  const int mb = wv & 1;
  const int nb = wv >> 1;

  f32x4 acc[4] = {};

  const int ar = tid >> 3;
  const int akk0 = (tid & 7) * 4;
  int arow = row0 + ar; if (arow >= N) arow = N - 1;
  const unsigned aaddr = ((unsigned)(ar * 64 + akk0 * 2)) ^ (((unsigned)(ar & 7)) << 4);

  const int rr = 16 * mb + (lane & 15);
  const unsigned aoff = ((unsigned)(rr * 64 + (lane >> 4) * 16)) ^ (((unsigned)(rr & 7)) << 4);

  for (int q = 0; q < 8; ++q) {
    {
      const f32x4 v = __builtin_nontemporal_load(
          (const f32x4*)(x + (size_t)arow * 256 + q * 32 + akk0));
      unsigned short h0 = f2bf(v[0]), h1 = f2bf(v[1]), h2 = f2bf(v[2]), h3 = f2bf(v[3]);
      unsigned short l0 = f2bf(v[0] - bfval(h0));
      unsigned short l1 = f2bf(v[1] - bfval(h1));
      unsigned short l2 = f2bf(v[2] - bfval(h2));
      unsigned short l3 = f2bf(v[3] - bfval(h3));
      *(uint2*)(smem + 16384 + aaddr) =
          make_uint2((unsigned)h0 | ((unsigned)h1 << 16), (unsigned)h2 | ((unsigned)h3 << 16));
      *(uint2*)(smem + 18432 + aaddr) =
          make_uint2((unsigned)l0 | ((unsigned)l1 << 16), (unsigned)l2 | ((unsigned)l3 << 16));
    }
    {
      const uint4* gb = (const uint4*)(wblob + (size_t)q * 16384);
      uint4* sb = (uint4*)smem;
      uint4 t0 = gb[tid], t1 = gb[tid + 256], t2 = gb[tid + 512], t3 = gb[tid + 768];
      sb[tid] = t0; sb[tid + 256] = t1; sb[tid + 512] = t2; sb[tid + 768] = t3;
    }
    __syncthreads();
    {
      const bf16x8 ah = *(const bf16x8*)(smem + 16384 + aoff);
      const bf16x8 al = *(const bf16x8*)(smem + 18432 + aoff);
      #pragma unroll
      for (int nf = 0; nf < 4; ++nf) {
        const int c = 64 * nb + 16 * nf + (lane & 15);
        const unsigned boff =
            ((unsigned)(c * 64 + (lane >> 4) * 16)) ^ (((unsigned)(c & 7)) << 4);
        const bf16x8 bh = *(const bf16x8*)(smem + boff);
        const bf16x8 bl = *(const bf16x8*)(smem + 8192 + boff);
        acc[nf] = __builtin_amdgcn_mfma_f32_16x16x32_bf16(ah, bh, acc[nf], 0, 0, 0);
        acc[nf] = __builtin_amdgcn_mfma_f32_16x16x32_bf16(ah, bl, acc[nf], 0, 0, 0);
        acc[nf] = __builtin_amdgcn_mfma_f32_16x16x32_bf16(al, bh, acc[nf], 0, 0, 0);
      }
    }
    __syncthreads();
  }

  #pragma unroll
  for (int nf = 0; nf < 4; ++nf) {
    const int col = 64 * nb + 16 * nf + (lane & 15);
    #pragma unroll
    for (int r = 0; r < 4; ++r) {
      const int row = row0 + 16 * mb + 4 * (lane >> 4) + r;
      if (row < N) h[(size_t)row * 128 + col] = f2bf(acc[nf][r]);
    }
  }
}

// ---------------- R13 cooperative mega-kernel ----------------
// P0: zero binTail + wprep.  P1: bin pass (no staging, 4x wave counters).
// P2: bucket-build (vb<nbins) || gemm tiles.  2 grid syncs.
__global__ __launch_bounds__(256) void k_mega(
    const float* __restrict__ x, const float* __restrict__ W,
    const int* __restrict__ src, const int* __restrict__ dst,
    unsigned short* __restrict__ wblob, u32x2* __restrict__ pairs,
    unsigned int* __restrict__ binTail, unsigned int* __restrict__ cnt,
    int* __restrict__ srcs, unsigned short* __restrict__ h,
    int N, int E, int nbins, int shift, int cap, int prepB, int gemmB)
{
  __shared__ __align__(16) unsigned char smem[20480];
  cg::grid_group grid = cg::this_grid();
  const int tid = threadIdx.x;
  const int nblk = (int)gridDim.x;
  const int gtid = (int)blockIdx.x * 256 + tid;
  const int gthreads = nblk * 256;

  // ---- P0: zero binTail + W prep
  for (int i = gtid; i < nbins; i += gthreads) binTail[i] = 0u;
  for (int g = gtid; g < 256 * 128; g += gthreads) wprep_elem(W, wblob, g);
  __threadfence();
  grid.sync();

  // ---- P1: bin pass
  for (int vb = (int)blockIdx.x; vb < prepB; vb += nblk) {
    unsigned int* lcnt4 = (unsigned int*)smem;            // [4][MAXB]
    unsigned int* lbase = lcnt4 + 4 * MAXB;               // [MAXB]
    unsigned int* loff  = lbase + MAXB;                   // [MAXB]
    __syncthreads();                                      // smem reuse guard
    for (int i = tid; i < 4 * MAXB; i += 256) lcnt4[i] = 0u;
    for (int i = tid; i < MAXB; i += 256) loff[i] = 0u;
    __syncthreads();
    const int e0 = vb * EPB;
    const int wv = tid >> 6;
    #pragma unroll
    for (int i = 0; i < EPB / 256; ++i) {
      const int e = e0 + i * 256 + tid;
      if (e < E) {
        int d = __builtin_nontemporal_load(dst + e);
        atomicAdd(&lcnt4[wv * MAXB + (d >> shift)], 1u);
      }
    }
    __syncthreads();
    if (tid < nbins) {
      unsigned c = lcnt4[tid] + lcnt4[MAXB + tid] + lcnt4[2 * MAXB + tid] + lcnt4[3 * MAXB + tid];
      lbase[tid] = c ? atomicAdd(&binTail[tid], c) : 0u;
    }
    __syncthreads();
    #pragma unroll
    for (int i = 0; i < EPB / 256; ++i) {
      const int e = e0 + i * 256 + tid;
      if (e < E) {
        int d = dst[e];                    // L1/L2-hot re-read
        int s = src[e];
        const int bin = d >> shift;
        const unsigned p = lbase[bin] + atomicAdd(&loff[bin], 1u);
        if (p < (unsigned)cap) {
          u32x2 o;
          o.x = (unsigned)d - ((unsigned)bin << shift);
          o.y = (unsigned)s;
          __builtin_nontemporal_store(o, pairs + (size_t)bin * cap + p);
        }
      }
    }
  }
  __threadfence();
  grid.sync();

  // ---- P2: bucket-build || gemm
  for (int vb = (int)blockIdx.x; vb < nbins + gemmB; vb += nblk) {
    __syncthreads();                                      // smem reuse guard
    if (vb < nbins)
      bucket_body(smem, vb, tid, pairs, binTail, cnt, srcs, N, shift, cap);
    else
      gemm_body(smem, vb - nbins, tid, x, (const unsigned char*)wblob, h, N);
  }
}

// ---------------- R12 fallback kernels (used only if coop launch fails)

__global__ __launch_bounds__(256) void k_prep_bin(
    const float* __restrict__ W, unsigned short* __restrict__ blob,
    const int* __restrict__ src, const int* __restrict__ dst,
    u32x2* __restrict__ pairs, unsigned int* __restrict__ binTail,
    int E, int nbins, int shift, int cap)
{
  __shared__ unsigned int lcnt4[4 * MAXB];
  __shared__ unsigned int lbase[MAXB], loff[MAXB];
  const int tid = threadIdx.x;
  const int id = blockIdx.x;

  if (id < 128) {
    wprep_elem(W, blob, id * 256 + tid);
    return;
  }
  for (int i = tid; i < 4 * MAXB; i += 256) lcnt4[i] = 0u;
  for (int i = tid; i < MAXB; i += 256) loff[i] = 0u;
  __syncthreads();
  const int e0 = (id - 128) * EPB;
  const int wv = tid >> 6;
  #pragma unroll
  for (int i = 0; i < EPB / 256; ++i) {
    const int e = e0 + i * 256 + tid;
    if (e < E) {
      int d = __builtin_nontemporal_load(dst + e);
      atomicAdd(&lcnt4[wv * MAXB + (d >> shift)], 1u);
    }
  }
  __syncthreads();
  if (tid < nbins) {
    unsigned c = lcnt4[tid] + lcnt4[MAXB + tid] + lcnt4[2 * MAXB + tid] + lcnt4[3 * MAXB + tid];
    lbase[tid] = c ? atomicAdd(&binTail[tid], c) : 0u;
  }
  __syncthreads();
  #pragma unroll
  for (int i = 0; i < EPB / 256; ++i) {
    const int e = e0 + i * 256 + tid;
    if (e < E) {
      int d = dst[e];
      int s = src[e];
      const int bin = d >> shift;
      const unsigned p = lbase[bin] + atomicAdd(&loff[bin], 1u);
      if (p < (unsigned)cap) {
        u32x2 o;
        o.x = (unsigned)d - ((unsigned)bin << shift);
        o.y = (unsigned)s;
        __builtin_nontemporal_store(o, pairs + (size_t)bin * cap + p);
      }
    }
  }
}

__global__ __launch_bounds__(256) void k_gemm_scatter(
    const float* __restrict__ x, const unsigned char* __restrict__ wblob,
    unsigned short* __restrict__ h, int N,
    const u32x2* __restrict__ pairs, const unsigned int* __restrict__ binTail,
    unsigned int* __restrict__ cnt, int* __restrict__ srcs,
    int nbins, int shift, int cap, int gemmB)
{
  __shared__ __align__(16) unsigned char smem[20480];
  const int id = blockIdx.x;
  const int tid = threadIdx.x;
  if (id < nbins) {
    bucket_body(smem, id, tid, pairs, binTail, cnt, srcs, N, shift, cap);
    return;
  }
  const int idx = id - nbins;
  if (idx >= gemmB) return;
  gemm_body(smem, idx, tid, x, wblob, h, N);
}

// Aggregation (unchanged): one wave64 per dst node.
__global__ __launch_bounds__(256) void k_aggr(
    const unsigned short* __restrict__ h, const int* __restrict__ srcs,
    const unsigned int* __restrict__ cnt,
    const float* __restrict__ b, float* __restrict__ out, int N)
{
  const int wid = (int)(((size_t)blockIdx.x * 256 + threadIdx.x) >> 6);  // node id
  if (wid >= N) return;                       // wave-uniform
  const int lane = threadIdx.x & 63;
  const int eg = lane >> 4;                   // 0..3
  const int cl = lane & 15;                   // 0..15
  const int deg = min((int)cnt[wid], 64);
  const int m = deg + 1;                      // + self
  const size_t coff = (size_t)(cl << 3);      // 8 channels per lane
  const size_t lbase = (size_t)wid << 6;

  float a0 = 0.f, a1 = 0.f, a2 = 0.f, a3 = 0.f, a4 = 0.f, a5 = 0.f, a6 = 0.f, a7 = 0.f;

  for (int base = 0; base < m; base += 64) {
    const int kk = min(64, m - base);
    const int slot = base + lane;
    int sidx = wid;
    if (slot < deg) sidx = srcs[lbase + slot];
    const float sd = rsqrtf((float)(cnt[sidx] + 1u));
    int j = 0;
    for (; j + 8 <= kk; j += 8) {             // 2 gathers in flight, 8 edges
      const int s0 = __shfl(sidx, j + eg, 64);
      const int s1 = __shfl(sidx, j + 4 + eg, 64);
      const float d0 = __shfl(sd, j + eg, 64);
      const float d1 = __shfl(sd, j + 4 + eg, 64);
      const uint4 v0 = *(const uint4*)(h + ((size_t)s0 << 7) + coff);
      const uint4 v1 = *(const uint4*)(h + ((size_t)s1 << 7) + coff);
      a0 = fmaf(bf0(v0.x), d0, a0); a1 = fmaf(bf1(v0.x), d0, a1);
      a2 = fmaf(bf0(v0.y), d0, a2); a3 = fmaf(bf1(v0.y), d0, a3);
      a4 = fmaf(bf0(v0.z), d0, a4); a5 = fmaf(bf1(v0.z), d0, a5);
      a6 = fmaf(bf0(v0.w), d0, a6); a7 = fmaf(bf1(v0.w), d0, a7);
      a0 = fmaf(bf0(v1.x), d1, a0); a1 = fmaf(bf1(v1.x), d1, a1);
      a2 = fmaf(bf0(v1.y), d1, a2); a3 = fmaf(bf1(v1.y), d1, a3);
      a4 = fmaf(bf0(v1.z), d1, a4); a5 = fmaf(bf1(v1.z), d1, a5);
      a6 = fmaf(bf0(v1.w), d1, a6); a7 = fmaf(bf1(v1.w), d1, a7);
    }
    for (; j < kk; j += 4) {                  // masked tail, 1-4 edges
      const int s0 = __shfl(sidx, j + eg, 64);
      const float d0 = __shfl(sd, j + eg, 64);
      if (j + eg < kk) {
        const uint4 v0 = *(const uint4*)(h + ((size_t)s0 << 7) + coff);
        a0 = fmaf(bf0(v0.x), d0, a0); a1 = fmaf(bf1(v0.x), d0, a1);
        a2 = fmaf(bf0(v0.y), d0, a2); a3 = fmaf(bf1(v0.y), d0, a3);
        a4 = fmaf(bf0(v0.z), d0, a4); a5 = fmaf(bf1(v0.z), d0, a5);
        a6 = fmaf(bf0(v0.w), d0, a6); a7 = fmaf(bf1(v0.w), d0, a7);
      }
    }
  }

  a0 += __shfl_xor(a0, 16, 64); a0 += __shfl_xor(a0, 32, 64);
  a1 += __shfl_xor(a1, 16, 64); a1 += __shfl_xor(a1, 32, 64);
  a2 += __shfl_xor(a2, 16, 64); a2 += __shfl_xor(a2, 32, 64);
  a3 += __shfl_xor(a3, 16, 64); a3 += __shfl_xor(a3, 32, 64);
  a4 += __shfl_xor(a4, 16, 64); a4 += __shfl_xor(a4, 32, 64);
  a5 += __shfl_xor(a5, 16, 64); a5 += __shfl_xor(a5, 32, 64);
  a6 += __shfl_xor(a6, 16, 64); a6 += __shfl_xor(a6, 32, 64);
  a7 += __shfl_xor(a7, 16, 64); a7 += __shfl_xor(a7, 32, 64);

  if (lane < 32) {
    const float dn = rsqrtf((float)m);
    const int hi = lane >> 4;                 // 0: regs a0..a3, 1: regs a4..a7
    const int c0 = ((lane & 15) << 3) + (hi << 2);
    const float4 bb = *(const float4*)(b + c0);
    const float r0 = hi ? a4 : a0;
    const float r1 = hi ? a5 : a1;
    const float r2 = hi ? a6 : a2;
    const float r3 = hi ? a7 : a3;
    float4 o;
    o.x = fmaxf(fmaf(dn, r0, bb.x), 0.f);
    o.y = fmaxf(fmaf(dn, r1, bb.y), 0.f);
    o.z = fmaxf(fmaf(dn, r2, bb.z), 0.f);
    o.w = fmaxf(fmaf(dn, r3, bb.w), 0.f);
    *(float4*)(out + ((size_t)wid << 7) + c0) = o;
  }
}

extern "C" void kernel_launch(void* const* d_in, const int* in_sizes, int n_in,
                              void* d_out, int out_size, void* d_ws, size_t ws_size,
                              hipStream_t stream)
{
  const float* x  = (const float*)d_in[0];
  const int* ei   = (const int*)d_in[1];
  const float* W  = (const float*)d_in[2];
  const float* b  = (const float*)d_in[3];
  float* out = (float*)d_out;

  const int Cout = in_sizes[3];            // 128
  const int Cin  = in_sizes[2] / Cout;     // 256
  const int N    = in_sizes[0] / Cin;      // 100000
  const int E    = in_sizes[1] / 2;        // 1600000

  const int* src = ei;
  const int* dst = ei + E;

  // bin geometry: nbins <= 256 (MAXB), bin size = 1<<shift nodes
  int shift = 9;
  while (((N + (1 << shift) - 1) >> shift) > MAXB) ++shift;
  const int nbins = (N + (1 << shift) - 1) >> shift;     // 196 here
  const int cap = E / nbins + E / (2 * nbins) + 1024;    // ~13.3k

  char* p = (char*)d_ws;
  size_t off = 0;
  auto alloc = [&](size_t bytes) { char* q = p + off; off = (off + bytes + 255) & ~(size_t)255; return q; };
  unsigned int* cnt = (unsigned int*)alloc((size_t)N * 4);
  int* srcs         = (int*)alloc((size_t)N * 64 * 4);              // stride-64 buckets
  unsigned short* h = (unsigned short*)alloc((size_t)N * Cout * 2); // bf16
  unsigned short* wblob = (unsigned short*)alloc(8 * 16384);        // 128KB LDS images
  unsigned int* binTail = (unsigned int*)alloc((size_t)nbins * 4);
  u32x2* pairs      = (u32x2*)alloc((size_t)nbins * cap * 8);       // ~20MB

  const int gemmB = (N + 31) / 32;         // 3125
  const int prepB = (E + EPB - 1) / EPB;   // 391

  // cooperative mega-kernel: 1024 blocks (4/CU at 20.5KB LDS, cap 7/CU)
  {
    int N_ = N, E_ = E, nbins_ = nbins, shift_ = shift, cap_ = cap;
    int prepB_ = prepB, gemmB_ = gemmB;
    const float* x_ = x; const float* W_ = W;
    const int* src_ = src; const int* dst_ = dst;
    unsigned short* wblob_ = wblob; u32x2* pairs_ = pairs;
    unsigned int* binTail_ = binTail; unsigned int* cnt_ = cnt;
    int* srcs_ = srcs; unsigned short* h_ = h;
    void* args[] = {
      (void*)&x_, (void*)&W_, (void*)&src_, (void*)&dst_,
      (void*)&wblob_, (void*)&pairs_, (void*)&binTail_, (void*)&cnt_,
      (void*)&srcs_, (void*)&h_,
      (void*)&N_, (void*)&E_, (void*)&nbins_, (void*)&shift_, (void*)&cap_,
      (void*)&prepB_, (void*)&gemmB_
    };
    hipError_t err = hipLaunchCooperativeKernel((const void*)k_mega,
                                                dim3(1024), dim3(256),
                                                args, 0, stream);
    if (err != hipSuccess) {
      // fallback: R12 4-op sequence
      (void)hipMemsetAsync(binTail, 0, (size_t)nbins * 4, stream);
      k_prep_bin<<<128 + prepB, 256, 0, stream>>>(W, wblob, src, dst,
                                                  pairs, binTail, E, nbins, shift, cap);
      k_gemm_scatter<<<nbins + gemmB, 256, 0, stream>>>(x, (const unsigned char*)wblob, h, N,
                                                        pairs, binTail, cnt, srcs,
                                                        nbins, shift, cap, gemmB);
    }
  }
  k_aggr<<<(N + 3) / 4, 256, 0, stream>>>(h, srcs, cnt, b, out, N);
}

// Round 7
// 343.879 us; speedup vs baseline: 2.0098x; 2.0098x over previous
//
#include <hip/hip_runtime.h>

// GCNConv + ReLU, MI355X. fp32 tensors, edge_index int32.
// out[d] = relu(dn * (h[d]*dn + sum_{e:dst=d} h[src_e]*dis[src_e]) + b),
//   h = x@W (UNSCALED bf16), dis[i] = rsqrt(cnt[i]+1), dn = dis[d].
// R8:  stride-64 buckets via 1.6M global atomicAdd.             334us
// R9:  GEMM VALU->MFMA (3-term bf16 split, swizzled W blob).    327us
// R10 FAILED (421): 8 edges/thread serialized atomic chains.
// R11: nt scatter/stream. fused 131->114.                       321us
// R12: two-level binning: fused 114->80, WRITE 123->60MB BUT    337us
//      serial bin pass ~50us sat in the critical path.
// R13 FAILED (691): cooperative mega-kernel; grid-wide phase
//      serialization + grid.sync spin; nt count-pass poisoned re-read.
//      Learned: inter-launch gap ~130-150us is harness-FIXED (not per
//      launch); only the serial kernel sum matters.
// R14: re-wire DAG: binpass ∥ GEMM in one launch (independent!),
//      then bucket (1024thr), then aggr (+nt out stores). Serial sum =
//      max(bin,gemm) + bucket + aggr. Binpass: no LDS staging, CACHED
//      loads both passes (re-read = L1/L2 hit), EPB 2048.

typedef __attribute__((ext_vector_type(8))) short bf16x8;
typedef __attribute__((ext_vector_type(4))) float f32x4;
typedef __attribute__((ext_vector_type(2))) unsigned int u32x2;

__device__ __forceinline__ unsigned short f2bf(float f) {
  unsigned int u = __float_as_uint(f);
  u += 0x7FFFu + ((u >> 16) & 1u);   // RNE
  return (unsigned short)(u >> 16);
}
__device__ __forceinline__ float bfval(unsigned short h) {
  return __uint_as_float(((unsigned int)h) << 16);
}
__device__ __forceinline__ float bf0(unsigned int u) { return __uint_as_float(u << 16); }
__device__ __forceinline__ float bf1(unsigned int u) { return __uint_as_float(u & 0xFFFF0000u); }

#define EPB 2048            // edges per bin block (256 thr x 8)
#define MAXB 256            // max bins

// W[256][128] -> per-K-chunk(32) LDS images (hi/lo bf16 split, XOR
// bank-swizzle baked in).
__global__ __launch_bounds__(256) void k_wprep(
    const float* __restrict__ W, unsigned short* __restrict__ blob)
{
  int g = blockIdx.x * 256 + threadIdx.x;     // 32768 = 256k x 128c
  int k = g >> 7, c = g & 127;
  float w = W[g];
  unsigned short hi = f2bf(w);
  unsigned short lo = f2bf(w - bfval(hi));
  int q = k >> 5, kk = k & 31;
  unsigned lin = (unsigned)(c * 64 + kk * 2);
  unsigned swz = lin ^ (((unsigned)(c & 7)) << 4);
  blob[(q * 16384 + swz) >> 1] = hi;
  blob[(q * 16384 + 8192 + swz) >> 1] = lo;
}

// One launch, two species:
// blocks [0,binB): bin pass. count (LDS, 4x wave counters, no-return
//   atomics) -> one global atomicAdd per (block,bin) -> place pairs
//   (cached re-read of L1-hot dst/src, nt pair stores).
// blocks [binB,binB+gemmB): gemm tiles (h = x@W -> bf16, MFMA), 4 waves,
//   tile 32 rows x 128 cols, K-chunk 32, 3-term bf16 split.
//   mfma_f32_16x16x32_bf16: A/B lane l: 8 contig k = 8*(l>>4)+j;
//   C/D: col = l&15, row = 4*(l>>4)+reg.
__global__ __launch_bounds__(256) void k_work(
    const float* __restrict__ x, const unsigned char* __restrict__ wblob,
    unsigned short* __restrict__ h, int N,
    const int* __restrict__ src, const int* __restrict__ dst,
    u32x2* __restrict__ pairs, unsigned int* __restrict__ binTail,
    int E, int nbins, int shift, int cap, int binB, int gemmB)
{
  // gemm: B images [0,16384), A hi [16384,18432), A lo [18432,20480)
  // bin:  lcnt4 [0,4096), lbase [4096,5120), loff [5120,6144)
  __shared__ __align__(16) unsigned char smem[20480];

  const int id = blockIdx.x;
  const int tid = threadIdx.x;

  if (id < binB) {                           // ---- bin pass
    unsigned int* lcnt4 = (unsigned int*)smem;            // [4][MAXB]
    unsigned int* lbase = lcnt4 + 4 * MAXB;               // [MAXB]
    unsigned int* loff  = lbase + MAXB;                   // [MAXB]
    for (int i = tid; i < 4 * MAXB; i += 256) lcnt4[i] = 0u;
    for (int i = tid; i < MAXB; i += 256) loff[i] = 0u;
    __syncthreads();
    const int e0 = id * EPB;
    const int wv = tid >> 6;
    #pragma unroll
    for (int i = 0; i < EPB / 256; ++i) {
      const int e = e0 + i * 256 + tid;
      if (e < E) {
        int d = dst[e];                                   // cached
        atomicAdd(&lcnt4[wv * MAXB + (d >> shift)], 1u);  // no-return
      }
    }
    __syncthreads();
    if (tid < nbins) {
      unsigned c = lcnt4[tid] + lcnt4[MAXB + tid] + lcnt4[2 * MAXB + tid] + lcnt4[3 * MAXB + tid];
      lbase[tid] = c ? atomicAdd(&binTail[tid], c) : 0u;
    }
    __syncthreads();
    #pragma unroll
    for (int i = 0; i < EPB / 256; ++i) {
      const int e = e0 + i * 256 + tid;
      if (e < E) {
        int d = dst[e];                                   // L1/L2 hit
        int s = src[e];
        const int bin = d >> shift;
        const unsigned p = lbase[bin] + atomicAdd(&loff[bin], 1u);
        if (p < (unsigned)cap) {
          u32x2 o;
          o.x = (unsigned)d - ((unsigned)bin << shift);
          o.y = (unsigned)s;
          __builtin_nontemporal_store(o, pairs + (size_t)bin * cap + p);
        }
      }
    }
    return;
  }

  const int idx = id - binB;
  if (idx >= gemmB) return;

  const int row0 = idx * 32;
  const int lane = tid & 63;
  const int wv = tid >> 6;
  const int mb = wv & 1;
  const int nb = wv >> 1;

  f32x4 acc[4] = {};

  const int ar = tid >> 3;
  const int akk0 = (tid & 7) * 4;
  int arow = row0 + ar; if (arow >= N) arow = N - 1;
  const unsigned aaddr = ((unsigned)(ar * 64 + akk0 * 2)) ^ (((unsigned)(ar & 7)) << 4);

  const int rr = 16 * mb + (lane & 15);
  const unsigned aoff = ((unsigned)(rr * 64 + (lane >> 4) * 16)) ^ (((unsigned)(rr & 7)) << 4);

  for (int q = 0; q < 8; ++q) {
    // ---- stage A: nt-load fp32 x, split to bf16 hi/lo, swizzled ds_write
    {
      const f32x4 v = __builtin_nontemporal_load(
          (const f32x4*)(x + (size_t)arow * 256 + q * 32 + akk0));
      unsigned short h0 = f2bf(v[0]), h1 = f2bf(v[1]), h2 = f2bf(v[2]), h3 = f2bf(v[3]);
      unsigned short l0 = f2bf(v[0] - bfval(h0));
      unsigned short l1 = f2bf(v[1] - bfval(h1));
      unsigned short l2 = f2bf(v[2] - bfval(h2));
      unsigned short l3 = f2bf(v[3] - bfval(h3));
      *(uint2*)(smem + 16384 + aaddr) =
          make_uint2((unsigned)h0 | ((unsigned)h1 << 16), (unsigned)h2 | ((unsigned)h3 << 16));
      *(uint2*)(smem + 18432 + aaddr) =
          make_uint2((unsigned)l0 | ((unsigned)l1 << 16), (unsigned)l2 | ((unsigned)l3 << 16));
    }
    // ---- stage B: identity-copy 16KB pre-swizzled image (L2-resident)
    {
      const uint4* gb = (const uint4*)(wblob + (size_t)q * 16384);
      uint4* sb = (uint4*)smem;
      uint4 t0 = gb[tid], t1 = gb[tid + 256], t2 = gb[tid + 512], t3 = gb[tid + 768];
      sb[tid] = t0; sb[tid + 256] = t1; sb[tid + 512] = t2; sb[tid + 768] = t3;
    }
    __syncthreads();
    // ---- MFMA: 4 n-frags x (hh + hl + lh)
    {
      const bf16x8 ah = *(const bf16x8*)(smem + 16384 + aoff);
      const bf16x8 al = *(const bf16x8*)(smem + 18432 + aoff);
      #pragma unroll
      for (int nf = 0; nf < 4; ++nf) {
        const int c = 64 * nb + 16 * nf + (lane & 15);
        const unsigned boff =
            ((unsigned)(c * 64 + (lane >> 4) * 16)) ^ (((unsigned)(c & 7)) << 4);
        const bf16x8 bh = *(const bf16x8*)(smem + boff);
        const bf16x8 bl = *(const bf16x8*)(smem + 8192 + boff);
        acc[nf] = __builtin_amdgcn_mfma_f32_16x16x32_bf16(ah, bh, acc[nf], 0, 0, 0);
        acc[nf] = __builtin_amdgcn_mfma_f32_16x16x32_bf16(ah, bl, acc[nf], 0, 0, 0);
        acc[nf] = __builtin_amdgcn_mfma_f32_16x16x32_bf16(al, bh, acc[nf], 0, 0, 0);
      }
    }
    __syncthreads();
  }

  // ---- epilogue: D frag (col=l&15, row=4*(l>>4)+r) -> bf16 h
  #pragma unroll
  for (int nf = 0; nf < 4; ++nf) {
    const int col = 64 * nb + 16 * nf + (lane & 15);
    #pragma unroll
    for (int r = 0; r < 4; ++r) {
      const int row = row0 + 16 * mb + 4 * (lane >> 4) + r;
      if (row < N) h[(size_t)row * 128 + col] = f2bf(acc[nf][r]);
    }
  }
}

// Bucket build: one 1024-thread block per bin. Replay the bin's pairs
// with LDS atomicInc into the bin's private 128KB srcs window; write
// cnt once per node (no memset needed).
__global__ __launch_bounds__(1024) void k_bucket(
    const u32x2* __restrict__ pairs, const unsigned int* __restrict__ binTail,
    unsigned int* __restrict__ cnt, int* __restrict__ srcs,
    int N, int shift, int cap)
{
  __shared__ unsigned int lcnt[1 << 9];       // bin size = 512 nodes
  const int bin = blockIdx.x;
  const int tid = threadIdx.x;
  const int bsz = 1 << shift;
  const int nbase = bin << shift;
  const int nn = min(bsz, N - nbase);
  if (nn <= 0) return;
  for (int i = tid; i < bsz; i += 1024) lcnt[i] = 0u;
  __syncthreads();
  const int n = min((int)binTail[bin], cap);
  const u32x2* bp = pairs + (size_t)bin * cap;
  for (int p = tid; p < n; p += 1024) {
    const u32x2 pr = __builtin_nontemporal_load(bp + p);
    const unsigned pos = atomicAdd(&lcnt[pr.x], 1u);
    if (pos < 64)
      srcs[(((size_t)(nbase + pr.x)) << 6) + pos] = (int)pr.y;
  }
  __syncthreads();
  for (int i = tid; i < nn; i += 1024) cnt[nbase + i] = lcnt[i];
}

// Aggregation: one wave64 per dst node. nt out stores (never re-read).
__global__ __launch_bounds__(256) void k_aggr(
    const unsigned short* __restrict__ h, const int* __restrict__ srcs,
    const unsigned int* __restrict__ cnt,
    const float* __restrict__ b, float* __restrict__ out, int N)
{
  const int wid = (int)(((size_t)blockIdx.x * 256 + threadIdx.x) >> 6);  // node id
  if (wid >= N) return;                       // wave-uniform
  const int lane = threadIdx.x & 63;
  const int eg = lane >> 4;                   // 0..3
  const int cl = lane & 15;                   // 0..15
  const int deg = min((int)cnt[wid], 64);
  const int m = deg + 1;                      // + self
  const size_t coff = (size_t)(cl << 3);      // 8 channels per lane
  const size_t lbase = (size_t)wid << 6;

  float a0 = 0.f, a1 = 0.f, a2 = 0.f, a3 = 0.f, a4 = 0.f, a5 = 0.f, a6 = 0.f, a7 = 0.f;

  for (int base = 0; base < m; base += 64) {
    const int kk = min(64, m - base);
    const int slot = base + lane;
    int sidx = wid;
    if (slot < deg) sidx = srcs[lbase + slot];
    const float sd = rsqrtf((float)(cnt[sidx] + 1u));
    int j = 0;
    for (; j + 8 <= kk; j += 8) {             // 2 gathers in flight, 8 edges
      const int s0 = __shfl(sidx, j + eg, 64);
      const int s1 = __shfl(sidx, j + 4 + eg, 64);
      const float d0 = __shfl(sd, j + eg, 64);
      const float d1 = __shfl(sd, j + 4 + eg, 64);
      const uint4 v0 = *(const uint4*)(h + ((size_t)s0 << 7) + coff);
      const uint4 v1 = *(const uint4*)(h + ((size_t)s1 << 7) + coff);
      a0 = fmaf(bf0(v0.x), d0, a0); a1 = fmaf(bf1(v0.x), d0, a1);
      a2 = fmaf(bf0(v0.y), d0, a2); a3 = fmaf(bf1(v0.y), d0, a3);
      a4 = fmaf(bf0(v0.z), d0, a4); a5 = fmaf(bf1(v0.z), d0, a5);
      a6 = fmaf(bf0(v0.w), d0, a6); a7 = fmaf(bf1(v0.w), d0, a7);
      a0 = fmaf(bf0(v1.x), d1, a0); a1 = fmaf(bf1(v1.x), d1, a1);
      a2 = fmaf(bf0(v1.y), d1, a2); a3 = fmaf(bf1(v1.y), d1, a3);
      a4 = fmaf(bf0(v1.z), d1, a4); a5 = fmaf(bf1(v1.z), d1, a5);
      a6 = fmaf(bf0(v1.w), d1, a6); a7 = fmaf(bf1(v1.w), d1, a7);
    }
    for (; j < kk; j += 4) {                  // masked tail, 1-4 edges
      const int s0 = __shfl(sidx, j + eg, 64);
      const float d0 = __shfl(sd, j + eg, 64);
      if (j + eg < kk) {
        const uint4 v0 = *(const uint4*)(h + ((size_t)s0 << 7) + coff);
        a0 = fmaf(bf0(v0.x), d0, a0); a1 = fmaf(bf1(v0.x), d0, a1);
        a2 = fmaf(bf0(v0.y), d0, a2); a3 = fmaf(bf1(v0.y), d0, a3);
        a4 = fmaf(bf0(v0.z), d0, a4); a5 = fmaf(bf1(v0.z), d0, a5);
        a6 = fmaf(bf0(v0.w), d0, a6); a7 = fmaf(bf1(v0.w), d0, a7);
      }
    }
  }

  a0 += __shfl_xor(a0, 16, 64); a0 += __shfl_xor(a0, 32, 64);
  a1 += __shfl_xor(a1, 16, 64); a1 += __shfl_xor(a1, 32, 64);
  a2 += __shfl_xor(a2, 16, 64); a2 += __shfl_xor(a2, 32, 64);
  a3 += __shfl_xor(a3, 16, 64); a3 += __shfl_xor(a3, 32, 64);
  a4 += __shfl_xor(a4, 16, 64); a4 += __shfl_xor(a4, 32, 64);
  a5 += __shfl_xor(a5, 16, 64); a5 += __shfl_xor(a5, 32, 64);
  a6 += __shfl_xor(a6, 16, 64); a6 += __shfl_xor(a6, 32, 64);
  a7 += __shfl_xor(a7, 16, 64); a7 += __shfl_xor(a7, 32, 64);

  if (lane < 32) {
    const float dn = rsqrtf((float)m);
    const int hi = lane >> 4;                 // 0: regs a0..a3, 1: regs a4..a7
    const int c0 = ((lane & 15) << 3) + (hi << 2);
    const float4 bb = *(const float4*)(b + c0);
    const float r0 = hi ? a4 : a0;
    const float r1 = hi ? a5 : a1;
    const float r2 = hi ? a6 : a2;
    const float r3 = hi ? a7 : a3;
    f32x4 o;
    o[0] = fmaxf(fmaf(dn, r0, bb.x), 0.f);
    o[1] = fmaxf(fmaf(dn, r1, bb.y), 0.f);
    o[2] = fmaxf(fmaf(dn, r2, bb.z), 0.f);
    o[3] = fmaxf(fmaf(dn, r3, bb.w), 0.f);
    __builtin_nontemporal_store(o, (f32x4*)(out + ((size_t)wid << 7) + c0));
  }
}

extern "C" void kernel_launch(void* const* d_in, const int* in_sizes, int n_in,
                              void* d_out, int out_size, void* d_ws, size_t ws_size,
                              hipStream_t stream)
{
  const float* x  = (const float*)d_in[0];
  const int* ei   = (const int*)d_in[1];
  const float* W  = (const float*)d_in[2];
  const float* b  = (const float*)d_in[3];
  float* out = (float*)d_out;

  const int Cout = in_sizes[3];            // 128
  const int Cin  = in_sizes[2] / Cout;     // 256
  const int N    = in_sizes[0] / Cin;      // 100000
  const int E    = in_sizes[1] / 2;        // 1600000

  const int* src = ei;
  const int* dst = ei + E;

  // bin geometry: nbins <= 256 (MAXB), bin size = 1<<shift nodes
  int shift = 9;
  while (((N + (1 << shift) - 1) >> shift) > MAXB) ++shift;
  const int nbins = (N + (1 << shift) - 1) >> shift;     // 196 here
  const int cap = E / nbins + E / (2 * nbins) + 1024;    // ~13.3k

  char* p = (char*)d_ws;
  size_t off = 0;
  auto alloc = [&](size_t bytes) { char* q = p + off; off = (off + bytes + 255) & ~(size_t)255; return q; };
  unsigned int* cnt = (unsigned int*)alloc((size_t)N * 4);
  int* srcs         = (int*)alloc((size_t)N * 64 * 4);              // stride-64 buckets
  unsigned short* h = (unsigned short*)alloc((size_t)N * Cout * 2); // bf16
  unsigned short* wblob = (unsigned short*)alloc(8 * 16384);        // 128KB LDS images
  unsigned int* binTail = (unsigned int*)alloc((size_t)nbins * 4);
  u32x2* pairs      = (u32x2*)alloc((size_t)nbins * cap * 8);       // ~21MB

  const int gemmB = (N + 31) / 32;         // 3125
  const int binB  = (E + EPB - 1) / EPB;   // 782

  (void)hipMemsetAsync(binTail, 0, (size_t)nbins * 4, stream);
  k_wprep<<<128, 256, 0, stream>>>(W, wblob);
  k_work<<<binB + gemmB, 256, 0, stream>>>(x, (const unsigned char*)wblob, h, N,
                                           src, dst, pairs, binTail,
                                           E, nbins, shift, cap, binB, gemmB);
  k_bucket<<<nbins, 1024, 0, stream>>>(pairs, binTail, cnt, srcs, N, shift, cap);
  k_aggr<<<(N + 3) / 4, 256, 0, stream>>>(h, srcs, cnt, b, out, N);
}

// Round 8
// 315.215 us; speedup vs baseline: 2.1925x; 1.0909x over previous
//
#include <hip/hip_runtime.h>

// GCNConv + ReLU, MI355X. fp32 tensors, edge_index int32.
// out[d] = relu(dn * (h[d]*dn + sum_{e:dst=d} h[src_e]*dis[src_e]) + b),
//   h = x@W (UNSCALED bf16), dis[i] = rsqrt(cnt[i]+1), dn = dis[d].
// R8:  stride-64 buckets via 1.6M global atomicAdd.             334us
// R9:  GEMM VALU->MFMA (3-term bf16 split, swizzled W blob).    327us
// R10 FAILED (421): 8 edges/thread serialized atomic chains.
// R11: nt scatter/stream. fused 131->114.                       321us
// R12: binning: fused 80 but serial binpass 50 in crit path.    337us
// R13 FAILED (691): cooperative mega-kernel, grid.sync spin.
// R14: binpass ∥ gemm: k_work 113 -> binpass costs the same ~43 344us
//      overlapped as direct scatter. Binning abandoned.
// Account: fixed harness overhead ~130-140us; aggr ~75 (needs all of
//      h/cnt/srcs -> unhideable); build stage floor = max(gemm,scatter).
// R15: back to R11 3-launch structure + 64x128 GEMM tile (24 MFMA per
//      16KB B-stage vs 12; blocks 3125->1563; wblob L2 traffic and
//      barrier count halved; LDS 24KB -> 6 blocks/CU).

typedef __attribute__((ext_vector_type(8))) short bf16x8;
typedef __attribute__((ext_vector_type(4))) float f32x4;

__device__ __forceinline__ unsigned short f2bf(float f) {
  unsigned int u = __float_as_uint(f);
  u += 0x7FFFu + ((u >> 16) & 1u);   // RNE
  return (unsigned short)(u >> 16);
}
__device__ __forceinline__ float bfval(unsigned short h) {
  return __uint_as_float(((unsigned int)h) << 16);
}
__device__ __forceinline__ float bf0(unsigned int u) { return __uint_as_float(u << 16); }
__device__ __forceinline__ float bf1(unsigned int u) { return __uint_as_float(u & 0xFFFF0000u); }

// Prologue: W[256][128] -> per-K-chunk(32) LDS images (hi/lo bf16 split,
// XOR bank-swizzle baked in), and zero cnt[N]. One launch.
__global__ __launch_bounds__(256) void k_wprep(
    const float* __restrict__ W, unsigned short* __restrict__ blob,
    unsigned int* __restrict__ cnt, int N)
{
  int g = blockIdx.x * 256 + threadIdx.x;
  if (g < N) cnt[g] = 0u;
  if (g >= 256 * 128) return;
  int k = g >> 7, c = g & 127;
  float w = W[g];
  unsigned short hi = f2bf(w);
  unsigned short lo = f2bf(w - bfval(hi));
  int q = k >> 5, kk = k & 31;
  unsigned lin = (unsigned)(c * 64 + kk * 2);
  unsigned swz = lin ^ (((unsigned)(c & 7)) << 4);
  blob[(q * 16384 + swz) >> 1] = hi;
  blob[(q * 16384 + 8192 + swz) >> 1] = lo;
}

// Fused: gemm tiles (h = x@W -> bf16, MFMA) and bucket scatter, 1:4
// interleaved (gemm block every 5th id). GEMM: 256 thr = 4 waves,
// tile 64 rows x 128 cols, K-chunk 32, 3-term bf16 split. Wave wv
// owns rows [16wv,16wv+16) x all 128 cols (8 n-frags).
// mfma_f32_16x16x32_bf16: A/B lane l: 8 contig k = 8*(l>>4)+j;
// C/D: col = l&15, row = 4*(l>>4)+reg.
__global__ __launch_bounds__(256) void k_gemm_scatter(
    const float* __restrict__ x, const unsigned char* __restrict__ wblob,
    unsigned short* __restrict__ h, int N,
    const int* __restrict__ src, const int* __restrict__ dst,
    unsigned int* __restrict__ cnt, int* __restrict__ srcs, int E,
    int gemmB, int scatB, int useIlv)
{
  // B images [0,16384), A hi [16384,20480), A lo [20480,24576)
  __shared__ __align__(16) unsigned char smem[24576];

  const int id = blockIdx.x;
  const int tid = threadIdx.x;
  bool isGemm;
  int idx;
  if (useIlv) {                         // 1 gemm : 4 scatter exact
    const int g = id / 5;
    if (id % 5 == 0) { isGemm = true;  idx = g; }
    else             { isGemm = false; idx = id - g - 1; }
  } else {                              // generic fallback: segmented
    isGemm = id < gemmB;
    idx = isGemm ? id : id - gemmB;
  }

  if (!isGemm) {
    if (idx < scatB) {
      int e = idx * 256 + tid;
      if (e < E) {
        int d = __builtin_nontemporal_load(dst + e);
        int s = __builtin_nontemporal_load(src + e);
        int pos = (int)atomicAdd(&cnt[d], 1u);
        if (pos < 64) __builtin_nontemporal_store(s, srcs + (((size_t)d << 6) + pos));
      }
    }
    return;
  }
  if (idx >= gemmB) return;

  const int row0 = idx * 64;
  const int lane = tid & 63;
  const int wv = tid >> 6;

  f32x4 acc[8] = {};

  // A-staging: each thread loads 2 rows (r, r+32), 4 k each
  const int ar = tid >> 3;              // 0..31
  const int akk0 = (tid & 7) * 4;
  int arow0 = row0 + ar;      if (arow0 >= N) arow0 = N - 1;
  int arow1 = row0 + ar + 32; if (arow1 >= N) arow1 = N - 1;
  const unsigned aaddr0 = ((unsigned)(ar * 64 + akk0 * 2)) ^ (((unsigned)(ar & 7)) << 4);
  const unsigned aaddr1 = ((unsigned)((ar + 32) * 64 + akk0 * 2)) ^ (((unsigned)((ar + 32) & 7)) << 4);

  // compute-side offsets: wave wv covers rows 16wv..16wv+15
  const int rr = 16 * wv + (lane & 15);
  const unsigned aoff = ((unsigned)(rr * 64 + (lane >> 4) * 16)) ^ (((unsigned)(rr & 7)) << 4);

  for (int q = 0; q < 8; ++q) {
    // ---- stage A: nt-load fp32 x (2 rows), split hi/lo, swizzled ds_write
    {
      const f32x4 v0 = __builtin_nontemporal_load(
          (const f32x4*)(x + (size_t)arow0 * 256 + q * 32 + akk0));
      const f32x4 v1 = __builtin_nontemporal_load(
          (const f32x4*)(x + (size_t)arow1 * 256 + q * 32 + akk0));
      unsigned short h0 = f2bf(v0[0]), h1 = f2bf(v0[1]), h2 = f2bf(v0[2]), h3 = f2bf(v0[3]);
      unsigned short l0 = f2bf(v0[0] - bfval(h0));
      unsigned short l1 = f2bf(v0[1] - bfval(h1));
      unsigned short l2 = f2bf(v0[2] - bfval(h2));
      unsigned short l3 = f2bf(v0[3] - bfval(h3));
      *(uint2*)(smem + 16384 + aaddr0) =
          make_uint2((unsigned)h0 | ((unsigned)h1 << 16), (unsigned)h2 | ((unsigned)h3 << 16));
      *(uint2*)(smem + 20480 + aaddr0) =
          make_uint2((unsigned)l0 | ((unsigned)l1 << 16), (unsigned)l2 | ((unsigned)l3 << 16));
      unsigned short h4 = f2bf(v1[0]), h5 = f2bf(v1[1]), h6 = f2bf(v1[2]), h7 = f2bf(v1[3]);
      unsigned short l4 = f2bf(v1[0] - bfval(h4));
      unsigned short l5 = f2bf(v1[1] - bfval(h5));
      unsigned short l6 = f2bf(v1[2] - bfval(h6));
      unsigned short l7 = f2bf(v1[3] - bfval(h7));
      *(uint2*)(smem + 16384 + aaddr1) =
          make_uint2((unsigned)h4 | ((unsigned)h5 << 16), (unsigned)h6 | ((unsigned)h7 << 16));
      *(uint2*)(smem + 20480 + aaddr1) =
          make_uint2((unsigned)l4 | ((unsigned)l5 << 16), (unsigned)l6 | ((unsigned)l7 << 16));
    }
    // ---- stage B: identity-copy 16KB pre-swizzled image (L2-resident)
    {
      const uint4* gb = (const uint4*)(wblob + (size_t)q * 16384);
      uint4* sb = (uint4*)smem;
      uint4 t0 = gb[tid], t1 = gb[tid + 256], t2 = gb[tid + 512], t3 = gb[tid + 768];
      sb[tid] = t0; sb[tid + 256] = t1; sb[tid + 512] = t2; sb[tid + 768] = t3;
    }
    __syncthreads();
    // ---- MFMA: 8 n-frags x (hh + hl + lh)
    {
      const bf16x8 ah = *(const bf16x8*)(smem + 16384 + aoff);
      const bf16x8 al = *(const bf16x8*)(smem + 20480 + aoff);
      #pragma unroll
      for (int nf = 0; nf < 8; ++nf) {
        const int c = 16 * nf + (lane & 15);
        const unsigned boff =
            ((unsigned)(c * 64 + (lane >> 4) * 16)) ^ (((unsigned)(c & 7)) << 4);
        const bf16x8 bh = *(const bf16x8*)(smem + boff);
        const bf16x8 bl = *(const bf16x8*)(smem + 8192 + boff);
        acc[nf] = __builtin_amdgcn_mfma_f32_16x16x32_bf16(ah, bh, acc[nf], 0, 0, 0);
        acc[nf] = __builtin_amdgcn_mfma_f32_16x16x32_bf16(ah, bl, acc[nf], 0, 0, 0);
        acc[nf] = __builtin_amdgcn_mfma_f32_16x16x32_bf16(al, bh, acc[nf], 0, 0, 0);
      }
    }
    __syncthreads();
  }

  // ---- epilogue: D frag (col=l&15, row=4*(l>>4)+r) -> bf16 h
  #pragma unroll
  for (int nf = 0; nf < 8; ++nf) {
    const int col = 16 * nf + (lane & 15);
    #pragma unroll
    for (int r = 0; r < 4; ++r) {
      const int row = row0 + 16 * wv + 4 * (lane >> 4) + r;
      if (row < N) h[(size_t)row * 128 + col] = f2bf(acc[nf][r]);
    }
  }
}

// Aggregation: one wave64 per dst node. nt out stores (never re-read).
__global__ __launch_bounds__(256) void k_aggr(
    const unsigned short* __restrict__ h, const int* __restrict__ srcs,
    const unsigned int* __restrict__ cnt,
    const float* __restrict__ b, float* __restrict__ out, int N)
{
  const int wid = (int)(((size_t)blockIdx.x * 256 + threadIdx.x) >> 6);  // node id
  if (wid >= N) return;                       // wave-uniform
  const int lane = threadIdx.x & 63;
  const int eg = lane >> 4;                   // 0..3
  const int cl = lane & 15;                   // 0..15
  const int deg = min((int)cnt[wid], 64);
  const int m = deg + 1;                      // + self
  const size_t coff = (size_t)(cl << 3);      // 8 channels per lane
  const size_t lbase = (size_t)wid << 6;

  float a0 = 0.f, a1 = 0.f, a2 = 0.f, a3 = 0.f, a4 = 0.f, a5 = 0.f, a6 = 0.f, a7 = 0.f;

  for (int base = 0; base < m; base += 64) {
    const int kk = min(64, m - base);
    const int slot = base + lane;
    int sidx = wid;
    if (slot < deg) sidx = srcs[lbase + slot];
    const float sd = rsqrtf((float)(cnt[sidx] + 1u));
    int j = 0;
    for (; j + 8 <= kk; j += 8) {             // 2 gathers in flight, 8 edges
      const int s0 = __shfl(sidx, j + eg, 64);
      const int s1 = __shfl(sidx, j + 4 + eg, 64);
      const float d0 = __shfl(sd, j + eg, 64);
      const float d1 = __shfl(sd, j + 4 + eg, 64);
      const uint4 v0 = *(const uint4*)(h + ((size_t)s0 << 7) + coff);
      const uint4 v1 = *(const uint4*)(h + ((size_t)s1 << 7) + coff);
      a0 = fmaf(bf0(v0.x), d0, a0); a1 = fmaf(bf1(v0.x), d0, a1);
      a2 = fmaf(bf0(v0.y), d0, a2); a3 = fmaf(bf1(v0.y), d0, a3);
      a4 = fmaf(bf0(v0.z), d0, a4); a5 = fmaf(bf1(v0.z), d0, a5);
      a6 = fmaf(bf0(v0.w), d0, a6); a7 = fmaf(bf1(v0.w), d0, a7);
      a0 = fmaf(bf0(v1.x), d1, a0); a1 = fmaf(bf1(v1.x), d1, a1);
      a2 = fmaf(bf0(v1.y), d1, a2); a3 = fmaf(bf1(v1.y), d1, a3);
      a4 = fmaf(bf0(v1.z), d1, a4); a5 = fmaf(bf1(v1.z), d1, a5);
      a6 = fmaf(bf0(v1.w), d1, a6); a7 = fmaf(bf1(v1.w), d1, a7);
    }
    for (; j < kk; j += 4) {                  // masked tail, 1-4 edges
      const int s0 = __shfl(sidx, j + eg, 64);
      const float d0 = __shfl(sd, j + eg, 64);
      if (j + eg < kk) {
        const uint4 v0 = *(const uint4*)(h + ((size_t)s0 << 7) + coff);
        a0 = fmaf(bf0(v0.x), d0, a0); a1 = fmaf(bf1(v0.x), d0, a1);
        a2 = fmaf(bf0(v0.y), d0, a2); a3 = fmaf(bf1(v0.y), d0, a3);
        a4 = fmaf(bf0(v0.z), d0, a4); a5 = fmaf(bf1(v0.z), d0, a5);
        a6 = fmaf(bf0(v0.w), d0, a6); a7 = fmaf(bf1(v0.w), d0, a7);
      }
    }
  }

  a0 += __shfl_xor(a0, 16, 64); a0 += __shfl_xor(a0, 32, 64);
  a1 += __shfl_xor(a1, 16, 64); a1 += __shfl_xor(a1, 32, 64);
  a2 += __shfl_xor(a2, 16, 64); a2 += __shfl_xor(a2, 32, 64);
  a3 += __shfl_xor(a3, 16, 64); a3 += __shfl_xor(a3, 32, 64);
  a4 += __shfl_xor(a4, 16, 64); a4 += __shfl_xor(a4, 32, 64);
  a5 += __shfl_xor(a5, 16, 64); a5 += __shfl_xor(a5, 32, 64);
  a6 += __shfl_xor(a6, 16, 64); a6 += __shfl_xor(a6, 32, 64);
  a7 += __shfl_xor(a7, 16, 64); a7 += __shfl_xor(a7, 32, 64);

  if (lane < 32) {
    const float dn = rsqrtf((float)m);
    const int hi = lane >> 4;                 // 0: regs a0..a3, 1: regs a4..a7
    const int c0 = ((lane & 15) << 3) + (hi << 2);
    const float4 bb = *(const float4*)(b + c0);
    const float r0 = hi ? a4 : a0;
    const float r1 = hi ? a5 : a1;
    const float r2 = hi ? a6 : a2;
    const float r3 = hi ? a7 : a3;
    f32x4 o;
    o[0] = fmaxf(fmaf(dn, r0, bb.x), 0.f);
    o[1] = fmaxf(fmaf(dn, r1, bb.y), 0.f);
    o[2] = fmaxf(fmaf(dn, r2, bb.z), 0.f);
    o[3] = fmaxf(fmaf(dn, r3, bb.w), 0.f);
    __builtin_nontemporal_store(o, (f32x4*)(out + ((size_t)wid << 7) + c0));
  }
}

extern "C" void kernel_launch(void* const* d_in, const int* in_sizes, int n_in,
                              void* d_out, int out_size, void* d_ws, size_t ws_size,
                              hipStream_t stream)
{
  const float* x  = (const float*)d_in[0];
  const int* ei   = (const int*)d_in[1];
  const float* W  = (const float*)d_in[2];
  const float* b  = (const float*)d_in[3];
  float* out = (float*)d_out;

  const int Cout = in_sizes[3];            // 128
  const int Cin  = in_sizes[2] / Cout;     // 256
  const int N    = in_sizes[0] / Cin;      // 100000
  const int E    = in_sizes[1] / 2;        // 1600000

  const int* src = ei;
  const int* dst = ei + E;

  char* p = (char*)d_ws;
  size_t off = 0;
  auto alloc = [&](size_t bytes) { char* q = p + off; off = (off + bytes + 255) & ~(size_t)255; return q; };
  unsigned int* cnt = (unsigned int*)alloc((size_t)N * 4);
  int* srcs         = (int*)alloc((size_t)N * 64 * 4);              // stride-64 buckets
  unsigned short* h = (unsigned short*)alloc((size_t)N * Cout * 2); // bf16
  unsigned short* wblob = (unsigned short*)alloc(8 * 16384);        // 128KB LDS images

  const int gemmB = (N + 63) / 64;         // 1563
  const int scatB = (E + 255) / 256;       // 6250 (1 edge/thread)
  const int grid  = gemmB + scatB;         // 7813
  const int useIlv = (gemmB == (grid + 4) / 5) ? 1 : 0;  // 1:4 exact?

  const int prepThreads = (N > 256 * 128) ? N : 256 * 128;
  k_wprep<<<(prepThreads + 255) / 256, 256, 0, stream>>>(W, wblob, cnt, N);
  k_gemm_scatter<<<grid, 256, 0, stream>>>(x, (const unsigned char*)wblob, h, N,
                                           src, dst, cnt, srcs, E,
                                           gemmB, scatB, useIlv);
  k_aggr<<<(N + 3) / 4, 256, 0, stream>>>(h, srcs, cnt, b, out, N);
}